// Round 6
// baseline (23880.632 us; speedup 1.0000x reference)
//
#include <hip/hip_runtime.h>
#include <math.h>

// Problem constants (match reference)
constexpr int B_   = 64;
constexpr int T_   = 200;
constexpr int L_IN = 100;
constexpr int S_   = 8;
constexpr int XC_  = 16;
constexpr int H_   = 256;
constexpr int W_   = 128;
constexpr int O_   = 8;
constexpr int GR_  = 3 * H_;      // 768
constexpr int HXC  = H_ * XC_;    // 4096

constexpr int NTEAM = 16;         // teams
constexpr int TB    = 16;         // blocks per team
constexpr int NBAT  = 4;          // batches per team
constexpr int ZPB   = 64;         // z-rows per encoder sub-block

#define NT 1024

// Workspace layout (floats)
constexpr size_t OFF_WIHT = 0;                               // [24][768]
constexpr size_t OFF_WHHT = OFF_WIHT + 24ull * GR_;          // [256][768]
constexpr size_t OFF_W2T  = OFF_WHHT + (size_t)H_ * GR_;     // [128][4096] k-major
constexpr size_t OFF_KX   = OFF_W2T + (size_t)W_ * HXC;      // [16][2][16][64]
constexpr size_t OFF_SEQ  = OFF_KX + (size_t)NTEAM * 2 * TB * 64; // [16*16] uint
constexpr size_t WS_FLOATS = OFF_SEQ + (size_t)NTEAM * TB;   // ~3.09 MB

// Transpose: in is R x K row-major; out[k*R + j] = in[j*K + k]
__global__ void transpose_kernel(const float* __restrict__ in, float* __restrict__ out,
                                 int R, int K) {
    int o = blockIdx.x * blockDim.x + threadIdx.x;
    if (o < R * K) {
        int k = o / R;
        int j = o - k * R;
        out[o] = in[j * K + k];
    }
}

__global__ void init_seq_kernel(unsigned* __restrict__ seq, int n) {
    int i = blockIdx.x * blockDim.x + threadIdx.x;
    if (i < n) seq[i] = 0u;
}

__device__ __forceinline__ float softplus_f(float x) {
    return fmaxf(x, 0.f) + log1pf(expf(-fabsf(x)));
}
__device__ __forceinline__ float sigmoid_f(float x) {
    return 1.f / (1.f + expf(-x));
}

// ---------------------------------------------------------------------------
// Distributed kernel: 16-block XCD-LOCAL teams serving 4 batches.
// Team mapping: xcd = blk&7, s = blk>>3; tau = xcd + 8*(s>>4), j = s&15.
// Under round-robin dispatch all 16 blocks of a team land on ONE XCD, so the
// kx/seq exchange stays in that XCD's L2 (~200cyc) instead of crossing the
// fabric (~900cyc) — this was R5's regression. Protocol: RELAXED agent-scope
// atomics only (no acquire/release -> no L2 invalidation); placement is a
// performance heuristic only, correctness holds on any placement.
// ---------------------------------------------------------------------------
__global__ __launch_bounds__(NT, 4) void gru_cde_dist(
    const float* __restrict__ y_past,   // [B][L_IN][S]
    const float* __restrict__ tvals,    // [T]
    const float* __restrict__ cx,       // [B][T][XC-1]
    const float* __restrict__ wihT,     // [24][768]
    const float* __restrict__ whhT,     // [256][768]
    const float* __restrict__ gru_b,    // [768]
    const float* __restrict__ gru_bn,   // [256]
    const float* __restrict__ w0,       // [128][256] row-major
    const float* __restrict__ b0,       // [128]
    const float* __restrict__ w1,       // [128][128] row-major
    const float* __restrict__ b1,       // [128]
    const float* __restrict__ w2T,      // [128][4096] k-major
    const float* __restrict__ b2,       // [4096]
    const float* __restrict__ ro_w,     // [8][256]
    const float* __restrict__ ro_b,     // [8]
    float* __restrict__ kx,             // [16][2][16][64]
    unsigned* __restrict__ seq,         // [16*16]
    float* __restrict__ out)            // [B][100][8]
{
    const int blk = blockIdx.x;          // 0..255
    const int s_  = blk >> 3;            // slot within XCD (round-robin model)
    const int tau = (blk & 7) + 8 * (s_ >> 4);  // team (XCD-local)
    const int j   = s_ & 15;             // block-in-team
    const int bbq = j & 3;               // encoder: batch-in-team
    const int q   = j >> 2;              // encoder: quarter
    const int tid = threadIdx.x;

    __shared__ __align__(16) float z[NBAT][H_];
    __shared__ __align__(16) float zs[NBAT][H_];
    __shared__ __align__(16) float kb[5][NBAT][H_];
    __shared__ __align__(16) float a0s[NBAT][W_];
    __shared__ __align__(16) float a1s[NBAT][W_];
    __shared__ __align__(16) float red[NBAT][8][W_];
    __shared__ __align__(16) float4 red4[NBAT][16][64];
    __shared__ float gsum[192];
    __shared__ float gaux[ZPB];
    __shared__ float xb[S_ + XC_];
    __shared__ __align__(16) float dxs[NBAT][XC_];

    int  epoch = 0;
    bool dead  = false;
    float hh   = 0.f;
    float4 dx4 = make_float4(0.f, 0.f, 0.f, 0.f);

    // ---------------- Encoder: 100 GRU steps (4-block sub-teams) -------------
    const int   seg = tid >> 6;          // 0=reset,1=update,2=new (tid<192)
    const int   l63 = tid & 63;
    const int   grow = seg * H_ + q * ZPB + l63;
    const float gbr = (tid < 192) ? gru_b[grow] : 0.f;
    const float bnr = (tid < ZPB) ? gru_bn[q * ZPB + tid] : 0.f;
    const int   gbatch0 = tau * NBAT;    // first batch of team

    if (tid < NBAT * H_) z[tid >> 8][tid & 255] = 0.f;
    __syncthreads();

    for (int step = 0; step < L_IN; ++step) {
        if (tid < S_ + XC_) {
            float v;
            int gb_ = gbatch0 + bbq;
            if (tid < S_)                v = y_past[(gb_ * L_IN + step) * S_ + tid];
            else if (tid < S_ + XC_ - 1) v = cx[(gb_ * T_ + step) * (XC_ - 1) + (tid - S_)];
            else                         v = tvals[step];
            xb[tid] = v;
        }
        __syncthreads();
        if (tid < 192) {
            float ig = gbr;
            #pragma unroll
            for (int k = 0; k < S_ + XC_; ++k) ig += wihT[k * GR_ + grow] * xb[k];
            float hg = 0.f, hg2 = 0.f;
            #pragma unroll 8
            for (int k = 0; k < H_; k += 2) {
                hg  += whhT[k * GR_ + grow]       * z[bbq][k];
                hg2 += whhT[(k + 1) * GR_ + grow] * z[bbq][k + 1];
            }
            hg += hg2;
            if (seg < 2) gsum[tid] = ig + hg;
            else { gsum[tid] = ig; gaux[l63] = hg; }
        }
        __syncthreads();
        epoch++;
        if (tid < ZPB) {
            float rr = sigmoid_f(gsum[tid]);
            float uu = sigmoid_f(gsum[64 + tid]);
            float nn = tanhf(gsum[128 + tid] + rr * (gaux[tid] + bnr));
            float zo = z[bbq][q * ZPB + tid];
            float znew = nn + uu * (zo - nn);
            z[bbq][q * ZPB + tid] = znew;
            __hip_atomic_store(&kx[(((size_t)tau * 2 + (epoch & 1)) * TB + j) * 64 + tid],
                               znew, __ATOMIC_RELAXED, __HIP_MEMORY_SCOPE_AGENT);
        }
        __syncthreads();   // drains vmcnt: publish stores complete
        if (tid == 0)
            __hip_atomic_store(&seq[tau * TB + j], (unsigned)epoch,
                               __ATOMIC_RELAXED, __HIP_MEMORY_SCOPE_AGENT);
        asm volatile("" ::: "memory");
        {   // waves 0..2 each poll+gather one peer quarter
            const int w = tid >> 6;
            if (w < 3 && !dead) {
                const int qq = w + (w >= q);
                const int jj = (qq << 2) | bbq;
                unsigned* sp = &seq[tau * TB + jj];
                int guard = 0;
                while (__hip_atomic_load(sp, __ATOMIC_RELAXED,
                                         __HIP_MEMORY_SCOPE_AGENT) < (unsigned)epoch) {
                    __builtin_amdgcn_s_sleep(1);
                    if (++guard > (1 << 20)) { dead = true; break; }
                }
                float v = __hip_atomic_load(
                    &kx[(((size_t)tau * 2 + (epoch & 1)) * TB + jj) * 64 + l63],
                    __ATOMIC_RELAXED, __HIP_MEMORY_SCOPE_AGENT);
                z[bbq][qq * 64 + l63] = v;
            }
        }
        __syncthreads();
    }

    // ---------------- Transition: team-wide z broadcast ----------------------
    epoch++;
    if (tid < 64)
        __hip_atomic_store(&kx[(((size_t)tau * 2 + (epoch & 1)) * TB + j) * 64 + tid],
                           z[bbq][q * 64 + tid],
                           __ATOMIC_RELAXED, __HIP_MEMORY_SCOPE_AGENT);
    __syncthreads();
    if (tid == 0)
        __hip_atomic_store(&seq[tau * TB + j], (unsigned)epoch,
                           __ATOMIC_RELAXED, __HIP_MEMORY_SCOPE_AGENT);
    asm volatile("" ::: "memory");
    {
        const int w = tid >> 6, e = tid & 63;
        if (w != j && !dead) {
            unsigned* sp = &seq[tau * TB + w];
            int guard = 0;
            while (__hip_atomic_load(sp, __ATOMIC_RELAXED,
                                     __HIP_MEMORY_SCOPE_AGENT) < (unsigned)epoch) {
                __builtin_amdgcn_s_sleep(1);
                if (++guard > (1 << 20)) { dead = true; break; }
            }
        }
        float v = __hip_atomic_load(
            &kx[(((size_t)tau * 2 + (epoch & 1)) * TB + w) * 64 + e],
            __ATOMIC_RELAXED, __HIP_MEMORY_SCOPE_AGENT);
        z[w & 3][(w >> 2) * 64 + e] = v;
    }
    __syncthreads();

    // readout: blocks j<4 write batch gbatch0+j
    auto readout = [&](int idx) {
        if (j < NBAT && tid < 8 * 64) {
            int o  = tid >> 6;
            int kk = tid & 63;
            float4 wv = reinterpret_cast<const float4*>(ro_w)[o * 64 + kk];
            float4 zv = *reinterpret_cast<const float4*>(&z[j][kk * 4]);
            float p = wv.x * zv.x + wv.y * zv.y + wv.z * zv.z + wv.w * zv.w;
            p += __shfl_xor(p, 1);
            p += __shfl_xor(p, 2);
            p += __shfl_xor(p, 4);
            p += __shfl_xor(p, 8);
            p += __shfl_xor(p, 16);
            p += __shfl_xor(p, 32);
            if (kk == 0) out[((gbatch0 + j) * L_IN + idx) * O_ + o] = p + ro_b[o];
        }
    };

    readout(0);

    // ---------------- Register-resident weights for the ODE ------------------
    const int r  = tid & 127;      // a0/a1 output row
    const int g  = tid >> 7;       // a0/a1 split-K group 0..7
    const int kg = tid >> 6;       // W2 k-group 0..15 (8 k each)
    const int u  = tid & 63;       // W2 row-quad within block's 256 rows

    float4 w0r[8];
    {
        const float4* w04 = reinterpret_cast<const float4*>(w0);
        #pragma unroll
        for (int c = 0; c < 8; ++c) w0r[c] = w04[r * 64 + g * 8 + c];
    }
    float4 w1r[4];
    {
        const float4* w14 = reinterpret_cast<const float4*>(w1);
        #pragma unroll
        for (int c = 0; c < 4; ++c) w1r[c] = w14[r * 32 + g * 4 + c];
    }
    const float4* __restrict__ w2T4 = reinterpret_cast<const float4*>(w2T);
    float4 w2c[8];
    #pragma unroll
    for (int p = 0; p < 8; ++p)
        w2c[p] = w2T4[(size_t)(kg * 8 + p) * (HXC / 4) + j * 64 + u];

    const float b0r = b0[r];
    const float b1r = b1[r];
    float4 b2c = make_float4(0.f, 0.f, 0.f, 0.f);
    if (tid < 256) b2c = reinterpret_cast<const float4*>(b2)[j * 64 + u];

    // vf: one dopri5 stage. zin = z or zs. s in [0,5].
    auto vf = [&](const float (*zin)[H_], int s) {
        // a0 partials, 4 batches
        #pragma unroll
        for (int bb2 = 0; bb2 < NBAT; ++bb2) {
            const float4* z4 = reinterpret_cast<const float4*>(&zin[bb2][0]) + g * 8;
            float acc0 = 0.f, acc1 = 0.f;
            #pragma unroll
            for (int c = 0; c < 8; ++c) {
                float4 zv = z4[c];
                acc0 += w0r[c].x * zv.x + w0r[c].y * zv.y;
                acc1 += w0r[c].z * zv.z + w0r[c].w * zv.w;
            }
            red[bb2][g][r] = acc0 + acc1;
        }
        __syncthreads();
        if (tid < 512) {
            int bb2 = tid >> 7;
            float sa = b0r;
            #pragma unroll
            for (int gg = 0; gg < 8; ++gg) sa += red[bb2][gg][r];
            a0s[bb2][r] = softplus_f(sa);
        }
        __syncthreads();
        // a1 partials
        #pragma unroll
        for (int bb2 = 0; bb2 < NBAT; ++bb2) {
            const float4* a4 = reinterpret_cast<const float4*>(&a0s[bb2][0]) + g * 4;
            float acc0 = 0.f, acc1 = 0.f;
            #pragma unroll
            for (int c = 0; c < 4; ++c) {
                float4 av = a4[c];
                acc0 += w1r[c].x * av.x + w1r[c].y * av.y;
                acc1 += w1r[c].z * av.z + w1r[c].w * av.w;
            }
            red[bb2][g][r] = acc0 + acc1;
        }
        __syncthreads();
        if (tid < 512) {
            int bb2 = tid >> 7;
            float sa = b1r;
            #pragma unroll
            for (int gg = 0; gg < 8; ++gg) sa += red[bb2][gg][r];
            a1s[bb2][r] = softplus_f(sa);
        }
        __syncthreads();
        // W2 partials: register weights, 4 batches
        #pragma unroll
        for (int bb2 = 0; bb2 < NBAT; ++bb2) {
            const float4* a14 = reinterpret_cast<const float4*>(&a1s[bb2][0]);
            float4 av0 = a14[kg * 2], av1 = a14[kg * 2 + 1];
            float a[8] = {av0.x, av0.y, av0.z, av0.w, av1.x, av1.y, av1.z, av1.w};
            float4 acc = make_float4(0.f, 0.f, 0.f, 0.f);
            #pragma unroll
            for (int p = 0; p < 8; ++p) {
                acc.x += w2c[p].x * a[p]; acc.y += w2c[p].y * a[p];
                acc.z += w2c[p].z * a[p]; acc.w += w2c[p].w * a[p];
            }
            red4[bb2][kg][u] = acc;
        }
        __syncthreads();
        epoch++;
        // combine: 16-way k-reduce, tanh, dx-dot, publish 64 values
        if (tid < 256) {
            const int cb = tid >> 6;
            float4 sum = red4[cb][0][u];
            #pragma unroll
            for (int kk = 1; kk < 16; ++kk) {
                float4 t = red4[cb][kk][u];
                sum.x += t.x; sum.y += t.y; sum.z += t.z; sum.w += t.w;
            }
            float p = tanhf(sum.x + b2c.x) * dx4.x + tanhf(sum.y + b2c.y) * dx4.y
                    + tanhf(sum.z + b2c.z) * dx4.z + tanhf(sum.w + b2c.w) * dx4.w;
            p += __shfl_xor(p, 1);
            p += __shfl_xor(p, 2);
            if ((u & 3) == 0)
                __hip_atomic_store(
                    &kx[(((size_t)tau * 2 + (epoch & 1)) * TB + j) * 64 + cb * 16 + (u >> 2)],
                    p, __ATOMIC_RELAXED, __HIP_MEMORY_SCOPE_AGENT);
        }
        __syncthreads();   // drain publish stores
        if (tid == 0)
            __hip_atomic_store(&seq[tau * TB + j], (unsigned)epoch,
                               __ATOMIC_RELAXED, __HIP_MEMORY_SCOPE_AGENT);
        asm volatile("" ::: "memory");
        // gather (wave w handles peer w) + fused zs/z update
        {
            const int w = tid >> 6, e = tid & 63;
            if (w != j && !dead) {
                unsigned* sp = &seq[tau * TB + w];
                int guard = 0;
                while (__hip_atomic_load(sp, __ATOMIC_RELAXED,
                                         __HIP_MEMORY_SCOPE_AGENT) < (unsigned)epoch) {
                    __builtin_amdgcn_s_sleep(1);
                    if (++guard > (1 << 20)) { dead = true; break; }
                }
            }
            float v = __hip_atomic_load(
                &kx[(((size_t)tau * 2 + (epoch & 1)) * TB + w) * 64 + e],
                __ATOMIC_RELAXED, __HIP_MEMORY_SCOPE_AGENT);
            const int bg = e >> 4;
            const int ii = w * 16 + (e & 15);
            float zc = z[bg][ii];
            if (s == 0) {
                kb[0][bg][ii] = v;
                zs[bg][ii] = zc + hh * (0.2f * v);
            } else if (s == 1) {
                kb[1][bg][ii] = v;
                zs[bg][ii] = zc + hh * (0.075f * kb[0][bg][ii] + 0.225f * v);
            } else if (s == 2) {
                kb[2][bg][ii] = v;
                zs[bg][ii] = zc + hh * ((44.f / 45.f) * kb[0][bg][ii]
                                      - (56.f / 15.f) * kb[1][bg][ii]
                                      + (32.f / 9.f) * v);
            } else if (s == 3) {
                kb[3][bg][ii] = v;
                zs[bg][ii] = zc + hh * ((19372.f / 6561.f) * kb[0][bg][ii]
                                      - (25360.f / 2187.f) * kb[1][bg][ii]
                                      + (64448.f / 6561.f) * kb[2][bg][ii]
                                      - (212.f / 729.f) * v);
            } else if (s == 4) {
                kb[4][bg][ii] = v;
                zs[bg][ii] = zc + hh * ((9017.f / 3168.f) * kb[0][bg][ii]
                                      - (355.f / 33.f) * kb[1][bg][ii]
                                      + (46732.f / 5247.f) * kb[2][bg][ii]
                                      + (49.f / 176.f) * kb[3][bg][ii]
                                      - (5103.f / 18656.f) * v);
            } else {
                z[bg][ii] = zc + hh * ((35.f / 384.f) * kb[0][bg][ii]
                                     + (500.f / 1113.f) * kb[2][bg][ii]
                                     + (125.f / 192.f) * kb[3][bg][ii]
                                     - (2187.f / 6784.f) * kb[4][bg][ii]
                                     + (11.f / 84.f) * v);
            }
        }
        __syncthreads();
    };

    // ---------------- ODE: 99 intervals x 2 dopri5 substeps ------------------
    for (int i = 0; i < T_ - L_IN - 1; ++i) {
        float dt = tvals[L_IN + i + 1] - tvals[L_IN + i];
        hh = dt * 0.5f;   // N_SUB = 2
        if (tid < NBAT * XC_) {
            int b2i = tid >> 4, c = tid & 15;
            int gb_ = gbatch0 + b2i;
            float xa, xbv;
            if (c < XC_ - 1) {
                xa  = cx[(gb_ * T_ + L_IN + i) * (XC_ - 1) + c];
                xbv = cx[(gb_ * T_ + L_IN + i + 1) * (XC_ - 1) + c];
            } else {
                xa  = tvals[L_IN + i];
                xbv = tvals[L_IN + i + 1];
            }
            dxs[b2i][c] = (xbv - xa) / dt;
        }
        __syncthreads();
        if (tid < 256) {
            int cb = tid >> 6;
            int c0 = (u & 3) * 4;
            dx4 = make_float4(dxs[cb][c0], dxs[cb][c0 + 1],
                              dxs[cb][c0 + 2], dxs[cb][c0 + 3]);
        }

        for (int sub = 0; sub < 2; ++sub) {
            vf(z, 0);
            vf(zs, 1);
            vf(zs, 2);
            vf(zs, 3);
            vf(zs, 4);
            vf(zs, 5);
        }
        readout(i + 1);
    }
}

// ---------------------------------------------------------------------------
// Fallback (ws too small): monolithic kernel, original weight layouts.
// ---------------------------------------------------------------------------
__global__ __launch_bounds__(NT) void gru_cde_mono(
    const float* __restrict__ y_past, const float* __restrict__ tvals,
    const float* __restrict__ cx,
    const float* __restrict__ wih, const float* __restrict__ whh,
    const float* __restrict__ gru_b, const float* __restrict__ gru_bn,
    const float* __restrict__ w0, const float* __restrict__ b0,
    const float* __restrict__ w1, const float* __restrict__ b1,
    const float* __restrict__ w2, const float* __restrict__ b2,
    const float* __restrict__ ro_w, const float* __restrict__ ro_b,
    float* __restrict__ out)
{
    const int b   = blockIdx.x;
    const int tid = threadIdx.x;

    __shared__ __align__(16) float z[H_];
    __shared__ float zsv[H_];
    __shared__ float kbv[6][H_];
    __shared__ float a0v[W_];
    __shared__ float a1v[W_];
    __shared__ float redv[8][W_];
    __shared__ float gsum[GR_];
    __shared__ float gaux[H_];
    __shared__ float xb[S_ + XC_];
    __shared__ float dxsv[XC_];

    const float gb_t = (tid < GR_) ? gru_b[tid] : 0.f;
    const float bn_t = (tid < H_) ? gru_bn[tid] : 0.f;
    const float4 bb = reinterpret_cast<const float4*>(b2)[tid];

    if (tid < H_) z[tid] = 0.f;
    __syncthreads();

    for (int step = 0; step < L_IN; ++step) {
        if (tid < S_ + XC_) {
            float v;
            if (tid < S_)                v = y_past[(b * L_IN + step) * S_ + tid];
            else if (tid < S_ + XC_ - 1) v = cx[(b * T_ + step) * (XC_ - 1) + (tid - S_)];
            else                         v = tvals[step];
            xb[tid] = v;
        }
        __syncthreads();
        if (tid < GR_) {
            float ig = gb_t;
            #pragma unroll
            for (int k = 0; k < S_ + XC_; ++k) ig += wih[tid * (S_ + XC_) + k] * xb[k];
            float hg = 0.f;
            #pragma unroll 8
            for (int k = 0; k < H_; ++k) hg += whh[tid * H_ + k] * z[k];
            if (tid < 2 * H_) gsum[tid] = ig + hg;
            else { gsum[tid] = ig; gaux[tid - 2 * H_] = hg; }
        }
        __syncthreads();
        if (tid < H_) {
            float r = sigmoid_f(gsum[tid]);
            float u = sigmoid_f(gsum[tid + H_]);
            float n = tanhf(gsum[tid + 2 * H_] + r * (gaux[tid] + bn_t));
            z[tid] = n + u * (z[tid] - n);
        }
        __syncthreads();
    }

    auto readout = [&](int idx) {
        if (tid < 8 * 64) {
            int o  = tid >> 6;
            int kk = tid & 63;
            float4 wv = reinterpret_cast<const float4*>(ro_w)[o * 64 + kk];
            float4 zv = *reinterpret_cast<const float4*>(&z[kk * 4]);
            float p = wv.x * zv.x + wv.y * zv.y + wv.z * zv.z + wv.w * zv.w;
            p += __shfl_xor(p, 1);
            p += __shfl_xor(p, 2);
            p += __shfl_xor(p, 4);
            p += __shfl_xor(p, 8);
            p += __shfl_xor(p, 16);
            p += __shfl_xor(p, 32);
            if (kk == 0) out[(b * L_IN + idx) * O_ + o] = p + ro_b[o];
        }
    };

    readout(0);

    auto vf = [&](const float* zin, int s) {
        const int g = tid >> 7;
        const int r = tid & 127;
        {
            float acc = 0.f;
            const int k0 = g * 32;
            #pragma unroll 8
            for (int k = k0; k < k0 + 32; ++k) acc += w0[r * H_ + k] * zin[k];
            redv[g][r] = acc;
        }
        __syncthreads();
        if (tid < W_) {
            float sa = b0[tid];
            #pragma unroll
            for (int gg = 0; gg < 8; ++gg) sa += redv[gg][tid];
            a0v[tid] = softplus_f(sa);
        }
        __syncthreads();
        {
            float acc = 0.f;
            const int k0 = g * 16;
            #pragma unroll
            for (int k = k0; k < k0 + 16; ++k) acc += w1[r * W_ + k] * a0v[k];
            redv[g][r] = acc;
        }
        __syncthreads();
        if (tid < W_) {
            float sa = b1[tid];
            #pragma unroll
            for (int gg = 0; gg < 8; ++gg) sa += redv[gg][tid];
            a1v[tid] = softplus_f(sa);
        }
        __syncthreads();
        {
            float4 acc = make_float4(0.f, 0.f, 0.f, 0.f);
            const int jj = tid * 4;
            #pragma unroll 4
            for (int k = 0; k < W_; ++k) {
                float av = a1v[k];
                acc.x += w2[(jj + 0) * W_ + k] * av;
                acc.y += w2[(jj + 1) * W_ + k] * av;
                acc.z += w2[(jj + 2) * W_ + k] * av;
                acc.w += w2[(jj + 3) * W_ + k] * av;
            }
            const int c0 = jj & 15;
            float p = tanhf(acc.x + bb.x) * dxsv[c0]
                    + tanhf(acc.y + bb.y) * dxsv[c0 + 1]
                    + tanhf(acc.z + bb.z) * dxsv[c0 + 2]
                    + tanhf(acc.w + bb.w) * dxsv[c0 + 3];
            p += __shfl_xor(p, 1);
            p += __shfl_xor(p, 2);
            if ((tid & 3) == 0) kbv[s][tid >> 2] = p;
        }
        __syncthreads();
    };

    for (int i = 0; i < T_ - L_IN - 1; ++i) {
        float dt = tvals[L_IN + i + 1] - tvals[L_IN + i];
        if (tid < XC_) {
            float xa, xbv;
            if (tid < XC_ - 1) {
                xa  = cx[(b * T_ + L_IN + i) * (XC_ - 1) + tid];
                xbv = cx[(b * T_ + L_IN + i + 1) * (XC_ - 1) + tid];
            } else {
                xa  = tvals[L_IN + i];
                xbv = tvals[L_IN + i + 1];
            }
            dxsv[tid] = (xbv - xa) / dt;
        }
        const float hh = dt * 0.5f;
        __syncthreads();

        for (int sub = 0; sub < 2; ++sub) {
            vf(z, 0);
            if (tid < H_) zsv[tid] = z[tid] + hh * (0.2f * kbv[0][tid]);
            __syncthreads();
            vf(zsv, 1);
            if (tid < H_) zsv[tid] = z[tid] + hh * (0.075f * kbv[0][tid] + 0.225f * kbv[1][tid]);
            __syncthreads();
            vf(zsv, 2);
            if (tid < H_) zsv[tid] = z[tid] + hh * ((44.f / 45.f) * kbv[0][tid]
                                                - (56.f / 15.f) * kbv[1][tid]
                                                + (32.f / 9.f) * kbv[2][tid]);
            __syncthreads();
            vf(zsv, 3);
            if (tid < H_) zsv[tid] = z[tid] + hh * ((19372.f / 6561.f) * kbv[0][tid]
                                                - (25360.f / 2187.f) * kbv[1][tid]
                                                + (64448.f / 6561.f) * kbv[2][tid]
                                                - (212.f / 729.f) * kbv[3][tid]);
            __syncthreads();
            vf(zsv, 4);
            if (tid < H_) zsv[tid] = z[tid] + hh * ((9017.f / 3168.f) * kbv[0][tid]
                                                - (355.f / 33.f) * kbv[1][tid]
                                                + (46732.f / 5247.f) * kbv[2][tid]
                                                + (49.f / 176.f) * kbv[3][tid]
                                                - (5103.f / 18656.f) * kbv[4][tid]);
            __syncthreads();
            vf(zsv, 5);
            if (tid < H_) {
                z[tid] = z[tid] + hh * ((35.f / 384.f) * kbv[0][tid]
                                      + (500.f / 1113.f) * kbv[2][tid]
                                      + (125.f / 192.f) * kbv[3][tid]
                                      - (2187.f / 6784.f) * kbv[4][tid]
                                      + (11.f / 84.f) * kbv[5][tid]);
            }
            __syncthreads();
        }
        readout(i + 1);
    }
}

extern "C" void kernel_launch(void* const* d_in, const int* in_sizes, int n_in,
                              void* d_out, int out_size, void* d_ws, size_t ws_size,
                              hipStream_t stream) {
    const float* y_past = (const float*)d_in[0];
    const float* tvals  = (const float*)d_in[1];
    const float* cx     = (const float*)d_in[2];
    const float* wih    = (const float*)d_in[3];
    const float* whh    = (const float*)d_in[4];
    const float* gb     = (const float*)d_in[5];
    const float* gbn    = (const float*)d_in[6];
    const float* w0     = (const float*)d_in[7];
    const float* b0     = (const float*)d_in[8];
    const float* w1     = (const float*)d_in[9];
    const float* b1     = (const float*)d_in[10];
    const float* w2     = (const float*)d_in[11];
    const float* b2     = (const float*)d_in[12];
    const float* ro_w   = (const float*)d_in[13];
    const float* ro_b   = (const float*)d_in[14];
    float* out = (float*)d_out;

    if (ws_size >= WS_FLOATS * sizeof(float)) {
        float* ws = (float*)d_ws;
        auto launchT = [&](const float* in, float* o, int R, int K) {
            int n = R * K;
            transpose_kernel<<<(n + 255) / 256, 256, 0, stream>>>(in, o, R, K);
        };
        launchT(wih, ws + OFF_WIHT, GR_, S_ + XC_);
        launchT(whh, ws + OFF_WHHT, GR_, H_);
        launchT(w2,  ws + OFF_W2T,  HXC, W_);
        int nseq = NTEAM * TB;
        init_seq_kernel<<<1, 256, 0, stream>>>((unsigned*)(ws + OFF_SEQ), nseq);
        gru_cde_dist<<<NTEAM * TB, NT, 0, stream>>>(
            y_past, tvals, cx,
            ws + OFF_WIHT, ws + OFF_WHHT, gb, gbn,
            w0, b0, w1, b1, ws + OFF_W2T, b2,
            ro_w, ro_b, ws + OFF_KX, (unsigned*)(ws + OFF_SEQ), out);
    } else {
        gru_cde_mono<<<B_, NT, 0, stream>>>(
            y_past, tvals, cx,
            wih, whh, gb, gbn,
            w0, b0, w1, b1, w2, b2,
            ro_w, ro_b, out);
    }
}

// Round 7
// 13965.688 us; speedup vs baseline: 1.7100x; 1.7100x over previous
//
#include <hip/hip_runtime.h>
#include <math.h>

// Problem constants (match reference)
constexpr int B_   = 64;
constexpr int T_   = 200;
constexpr int L_IN = 100;
constexpr int S_   = 8;
constexpr int XC_  = 16;
constexpr int H_   = 256;
constexpr int W_   = 128;
constexpr int O_   = 8;
constexpr int GR_  = 3 * H_;      // 768
constexpr int HXC  = H_ * XC_;    // 4096

constexpr int NB   = 4;           // blocks per batch (team)
constexpr int ZPB  = 64;          // z-rows per block
constexpr int SLOT = 128;         // exchange payload slot (floats)

#define NT 1024

// Workspace layout (floats)
constexpr size_t OFF_WIHT = 0;                               // [24][768]
constexpr size_t OFF_WHHT = OFF_WIHT + 24ull * GR_;          // [256][768]
constexpr size_t OFF_W2T  = OFF_WHHT + (size_t)H_ * GR_;     // [128][4096] k-major
constexpr size_t OFF_KX   = OFF_W2T + (size_t)W_ * HXC;      // [64][2][4][SLOT]
constexpr size_t OFF_SEQ  = OFF_KX + (size_t)B_ * 2 * NB * SLOT; // [64][4][16] uint
constexpr size_t WS_FLOATS = OFF_SEQ + (size_t)B_ * NB * 16; // ~3.09 MB

// Transpose: in is R x K row-major; out[k*R + j] = in[j*K + k]
__global__ void transpose_kernel(const float* __restrict__ in, float* __restrict__ out,
                                 int R, int K) {
    int o = blockIdx.x * blockDim.x + threadIdx.x;
    if (o < R * K) {
        int k = o / R;
        int j = o - k * R;
        out[o] = in[j * K + k];
    }
}

__global__ void init_seq_kernel(unsigned* __restrict__ seq, int n) {
    int i = blockIdx.x * blockDim.x + threadIdx.x;
    if (i < n) seq[i] = 0u;
}

__device__ __forceinline__ float softplus_f(float x) {
    return fmaxf(x, 0.f) + log1pf(expf(-fabsf(x)));
}
__device__ __forceinline__ float sigmoid_f(float x) {
    return 1.f / (1.f + expf(-x));
}

// ---------------------------------------------------------------------------
// R7: 4-block teams {b, b+64, b+128, b+192}; fully-distributed ODE state.
// Per stage, blocks exchange ONLY the 128-float partial v = W0own @ zs_own
// (3-peer fan-in, relaxed agent-scope atomics — R4's proven protocol).
// k and z stay block-local (z exchanged once per interval for readout).
// W2 slice (512 KB) tiered: 48 k-planes in VGPRs + 32 in LDS + 48 streamed.
// LDS ~153 KB -> 1 block/CU, 256 blocks co-resident on 256 CUs.
// ---------------------------------------------------------------------------
__global__ __launch_bounds__(NT, 4) void gru_cde_dist(
    const float* __restrict__ y_past,   // [B][L_IN][S]
    const float* __restrict__ tvals,    // [T]
    const float* __restrict__ cx,       // [B][T][XC-1]
    const float* __restrict__ wihT,     // [24][768]
    const float* __restrict__ whhT,     // [256][768]
    const float* __restrict__ gru_b,    // [768]
    const float* __restrict__ gru_bn,   // [256]
    const float* __restrict__ w0,       // [128][256] row-major
    const float* __restrict__ b0,       // [128]
    const float* __restrict__ w1,       // [128][128] row-major
    const float* __restrict__ b1,       // [128]
    const float* __restrict__ w2T,      // [128][4096] k-major
    const float* __restrict__ b2,       // [4096]
    const float* __restrict__ ro_w,     // [8][256]
    const float* __restrict__ ro_b,     // [8]
    float* __restrict__ kx,             // [64][2][4][SLOT]
    unsigned* __restrict__ seq,         // [64][4][16]
    float* __restrict__ out)            // [B][100][8]
{
    const int b   = blockIdx.x & (B_ - 1);   // batch; team = {b, b+64, b+128, b+192}
    const int q   = blockIdx.x >> 6;         // quarter 0..3
    const int tid = threadIdx.x;

    __shared__ __align__(16) float z[H_];        // full z (peers' quarters valid
                                                 // only after per-interval exchange)
    __shared__ __align__(16) float zsq[ZPB];     // own-quarter stage state
    __shared__ float kbq[5][ZPB];                // own-quarter k history
    __shared__ __align__(16) float a0s[W_];
    __shared__ __align__(16) float a1s[W_];
    __shared__ float vown[W_];
    __shared__ __align__(16) float red[8][W_];   // split-K partials
    __shared__ __align__(16) float4 red4[4][256];
    __shared__ float gsum[192];
    __shared__ float gaux[ZPB];
    __shared__ float xb[S_ + XC_];
    __shared__ float dxs[XC_];
    __shared__ __align__(16) float4 w2lds[4][8][256];  // 128 KB: 32 W2 k-planes

    int  epoch = 0;
    bool dead  = false;
    float hh   = 0.f;

    auto kxbase = [&](int qq) -> size_t {
        return (((size_t)b * 2 + (epoch & 1)) * NB + qq) * SLOT;
    };

    // ---------------- Encoder: 100 GRU steps (R4-proven) ---------------------
    const int   seg = tid >> 6;          // 0=reset,1=update,2=new (tid<192)
    const int   l63 = tid & 63;
    const int   grow = seg * H_ + q * ZPB + l63;
    const float gbr = (tid < 192) ? gru_b[grow] : 0.f;
    const float bnr = (tid < ZPB) ? gru_bn[q * ZPB + tid] : 0.f;

    if (tid < H_) z[tid] = 0.f;
    __syncthreads();

    for (int step = 0; step < L_IN; ++step) {
        if (tid < S_ + XC_) {
            float v;
            if (tid < S_)                v = y_past[(b * L_IN + step) * S_ + tid];
            else if (tid < S_ + XC_ - 1) v = cx[(b * T_ + step) * (XC_ - 1) + (tid - S_)];
            else                         v = tvals[step];
            xb[tid] = v;
        }
        __syncthreads();
        if (tid < 192) {
            float ig = gbr;
            #pragma unroll
            for (int k = 0; k < S_ + XC_; ++k) ig += wihT[k * GR_ + grow] * xb[k];
            float hg = 0.f, hg2 = 0.f;
            #pragma unroll 8
            for (int k = 0; k < H_; k += 2) {
                hg  += whhT[k * GR_ + grow]       * z[k];
                hg2 += whhT[(k + 1) * GR_ + grow] * z[k + 1];
            }
            hg += hg2;
            if (seg < 2) gsum[tid] = ig + hg;
            else { gsum[tid] = ig; gaux[l63] = hg; }
        }
        __syncthreads();
        epoch++;
        if (tid < ZPB) {
            float rr = sigmoid_f(gsum[tid]);
            float uu = sigmoid_f(gsum[64 + tid]);
            float nn = tanhf(gsum[128 + tid] + rr * (gaux[tid] + bnr));
            float zo = z[q * ZPB + tid];
            float znew = nn + uu * (zo - nn);
            z[q * ZPB + tid] = znew;
            __hip_atomic_store(&kx[kxbase(q) + tid], znew,
                               __ATOMIC_RELAXED, __HIP_MEMORY_SCOPE_AGENT);
        }
        __syncthreads();   // drains vmcnt: publish stores at coherence point
        if (tid == 0)
            __hip_atomic_store(&seq[(b * NB + q) * 16], (unsigned)epoch,
                               __ATOMIC_RELAXED, __HIP_MEMORY_SCOPE_AGENT);
        asm volatile("" ::: "memory");
        {   // waves 0..2 each poll+gather one peer quarter
            const int w = tid >> 6;
            if (w < 3 && !dead) {
                const int qq = w + (w >= q);
                unsigned* sp = &seq[(b * NB + qq) * 16];
                int guard = 0;
                while (__hip_atomic_load(sp, __ATOMIC_RELAXED,
                                         __HIP_MEMORY_SCOPE_AGENT) < (unsigned)epoch) {
                    __builtin_amdgcn_s_sleep(1);
                    if (++guard > (1 << 20)) { dead = true; break; }
                }
                float v = __hip_atomic_load(&kx[kxbase(qq) + l63],
                                            __ATOMIC_RELAXED, __HIP_MEMORY_SCOPE_AGENT);
                z[qq * 64 + l63] = v;
            }
        }
        __syncthreads();
    }

    // readout (block q==0 only; z full)
    auto readout = [&](int idx) {
        if (q == 0 && tid < 8 * 64) {
            int o  = tid >> 6;
            int kk = tid & 63;
            float4 wv = reinterpret_cast<const float4*>(ro_w)[o * 64 + kk];
            float4 zv = *reinterpret_cast<const float4*>(&z[kk * 4]);
            float p = wv.x * zv.x + wv.y * zv.y + wv.z * zv.z + wv.w * zv.w;
            p += __shfl_xor(p, 1);
            p += __shfl_xor(p, 2);
            p += __shfl_xor(p, 4);
            p += __shfl_xor(p, 8);
            p += __shfl_xor(p, 16);
            p += __shfl_xor(p, 32);
            if (kk == 0) out[(b * L_IN + idx) * O_ + o] = p + ro_b[o];
        }
    };

    readout(0);

    // ---------------- ODE setup: register + LDS weight residency -------------
    const int r  = tid & 127;      // output row for v / a1 split-K
    const int cs = tid >> 7;       // split-K group 0..7
    const int g2 = tid >> 8;       // W2 k-group 0..3 (32 k each)
    const int u  = tid & 255;      // W2 row-quad within block's 1024 rows

    // W0 own-columns slice: thread covers row r, cols q*64 + cs*8 .. +7
    float w0r[8];
    #pragma unroll
    for (int m = 0; m < 8; ++m) w0r[m] = w0[r * H_ + q * 64 + cs * 8 + m];
    // W1 rows: thread covers row r, k cols cs*16 .. +15
    float4 w1r[4];
    {
        const float4* w14 = reinterpret_cast<const float4*>(w1);
        #pragma unroll
        for (int c = 0; c < 4; ++c) w1r[c] = w14[r * 32 + cs * 4 + c];
    }
    const float4* __restrict__ w2T4 = reinterpret_cast<const float4*>(w2T);
    // W2 registers: k-planes j=0..11 of this thread's k-group
    float4 w2c[12];
    #pragma unroll
    for (int j = 0; j < 12; ++j)
        w2c[j] = w2T4[(size_t)(g2 * 32 + j) * (HXC / 4) + q * 256 + u];
    // W2 LDS: k-planes j=12..19 of each k-group (32 planes, 128 KB), once
    for (int it = 0; it < 8; ++it) {
        int L   = tid + 1024 * it;
        int g2l = L >> 11;
        int rem = L & 2047;
        int jj  = rem >> 8;
        int ul  = rem & 255;
        w2lds[g2l][jj][ul] =
            w2T4[(size_t)(g2l * 32 + 12 + jj) * (HXC / 4) + q * 256 + ul];
    }

    const float b0r = b0[r];
    const float b1r = b1[r];
    float4 b2c = make_float4(0.f, 0.f, 0.f, 0.f);
    if (tid < 256) b2c = reinterpret_cast<const float4*>(b2)[q * 256 + tid];
    float4 dx4 = make_float4(0.f, 0.f, 0.f, 0.f);
    __syncthreads();   // w2lds ready

    // ---------------- ODE: 99 intervals x 2 dopri5 substeps ------------------
    for (int i = 0; i < T_ - L_IN - 1; ++i) {
        float dt = tvals[L_IN + i + 1] - tvals[L_IN + i];
        hh = dt * 0.5f;   // N_SUB = 2
        if (tid < XC_) {
            float xa, xbv;
            if (tid < XC_ - 1) {
                xa  = cx[(b * T_ + L_IN + i) * (XC_ - 1) + tid];
                xbv = cx[(b * T_ + L_IN + i + 1) * (XC_ - 1) + tid];
            } else {
                xa  = tvals[L_IN + i];
                xbv = tvals[L_IN + i + 1];
            }
            dxs[tid] = (xbv - xa) / dt;
        }
        __syncthreads();
        if (tid < 256) {
            int c0 = (tid & 3) * 4;
            dx4 = make_float4(dxs[c0], dxs[c0 + 1], dxs[c0 + 2], dxs[c0 + 3]);
        }

        for (int sub = 0; sub < 2; ++sub) {
            if (tid < ZPB) zsq[tid] = z[q * ZPB + tid];
            __syncthreads();

            for (int s = 0; s < 6; ++s) {
                // ---- V: partial v = W0own @ zsq (8-way split-K over 64) ----
                {
                    float pv = 0.f;
                    #pragma unroll
                    for (int m = 0; m < 8; ++m) pv += w0r[m] * zsq[cs * 8 + m];
                    red[cs][r] = pv;
                }
                __syncthreads();
                epoch++;
                if (tid < W_) {
                    float v = red[0][tid] + red[1][tid] + red[2][tid] + red[3][tid]
                            + red[4][tid] + red[5][tid] + red[6][tid] + red[7][tid];
                    vown[tid] = v;
                    __hip_atomic_store(&kx[kxbase(q) + tid], v,
                                       __ATOMIC_RELAXED, __HIP_MEMORY_SCOPE_AGENT);
                }
                __syncthreads();   // drain publish stores
                if (tid == 0)
                    __hip_atomic_store(&seq[(b * NB + q) * 16], (unsigned)epoch,
                                       __ATOMIC_RELAXED, __HIP_MEMORY_SCOPE_AGENT);
                asm volatile("" ::: "memory");
                if (tid < NB && tid != q && !dead) {
                    unsigned* sp = &seq[(b * NB + tid) * 16];
                    int guard = 0;
                    while (__hip_atomic_load(sp, __ATOMIC_RELAXED,
                                             __HIP_MEMORY_SCOPE_AGENT) < (unsigned)epoch) {
                        __builtin_amdgcn_s_sleep(1);
                        if (++guard > (1 << 20)) { dead = true; break; }
                    }
                }
                __syncthreads();
                // ---- G: a0 = softplus(sum of 4 partials + b0) ----
                if (tid < W_) {
                    float gv = vown[tid] + b0r;
                    #pragma unroll
                    for (int qq = 0; qq < NB; ++qq) {
                        if (qq == q) continue;
                        gv += __hip_atomic_load(&kx[kxbase(qq) + tid],
                                                __ATOMIC_RELAXED,
                                                __HIP_MEMORY_SCOPE_AGENT);
                    }
                    a0s[tid] = softplus_f(gv);
                }
                __syncthreads();
                // ---- A1: a1 = softplus(W1 @ a0 + b1), 8-way split-K ----
                {
                    float pa0 = 0.f, pa1 = 0.f;
                    #pragma unroll
                    for (int c = 0; c < 4; ++c) {
                        float4 av = reinterpret_cast<const float4*>(a0s)[cs * 4 + c];
                        pa0 += w1r[c].x * av.x + w1r[c].y * av.y;
                        pa1 += w1r[c].z * av.z + w1r[c].w * av.w;
                    }
                    red[cs][r] = pa0 + pa1;
                }
                __syncthreads();
                if (tid < W_) {
                    float sa = b1r + red[0][tid] + red[1][tid] + red[2][tid] + red[3][tid]
                             + red[4][tid] + red[5][tid] + red[6][tid] + red[7][tid];
                    a1s[tid] = softplus_f(sa);
                }
                __syncthreads();
                // ---- W2: 12 reg + 8 LDS + 12 streamed k-planes ----
                {
                    float4 acc = make_float4(0.f, 0.f, 0.f, 0.f);
                    #pragma unroll
                    for (int j = 0; j < 12; ++j) {
                        float av = a1s[g2 * 32 + j];
                        acc.x += w2c[j].x * av; acc.y += w2c[j].y * av;
                        acc.z += w2c[j].z * av; acc.w += w2c[j].w * av;
                    }
                    #pragma unroll
                    for (int j = 0; j < 8; ++j) {
                        float4 wv = w2lds[g2][j][u];
                        float av = a1s[g2 * 32 + 12 + j];
                        acc.x += wv.x * av; acc.y += wv.y * av;
                        acc.z += wv.z * av; acc.w += wv.w * av;
                    }
                    const float4* wp = w2T4 + (size_t)(g2 * 32 + 20) * (HXC / 4)
                                     + q * 256 + u;
                    #pragma unroll 4
                    for (int j = 0; j < 12; ++j) {
                        float4 wv = wp[(size_t)j * (HXC / 4)];
                        float av = a1s[g2 * 32 + 20 + j];
                        acc.x += wv.x * av; acc.y += wv.y * av;
                        acc.z += wv.z * av; acc.w += wv.w * av;
                    }
                    red4[g2][u] = acc;
                }
                __syncthreads();
                // ---- K: 4-way k-reduce, tanh, dx-dot; update zsq / z ----
                if (tid < 256) {
                    float4 t0 = red4[0][tid], t1 = red4[1][tid];
                    float4 t2 = red4[2][tid], t3 = red4[3][tid];
                    float p = tanhf(t0.x + t1.x + t2.x + t3.x + b2c.x) * dx4.x
                            + tanhf(t0.y + t1.y + t2.y + t3.y + b2c.y) * dx4.y
                            + tanhf(t0.z + t1.z + t2.z + t3.z + b2c.z) * dx4.z
                            + tanhf(t0.w + t1.w + t2.w + t3.w + b2c.w) * dx4.w;
                    p += __shfl_xor(p, 1);
                    p += __shfl_xor(p, 2);
                    if ((tid & 3) == 0) {
                        int ii = tid >> 2;
                        float kv = p;
                        float zc = z[q * ZPB + ii];
                        if (s == 0) {
                            kbq[0][ii] = kv;
                            zsq[ii] = zc + hh * (0.2f * kv);
                        } else if (s == 1) {
                            kbq[1][ii] = kv;
                            zsq[ii] = zc + hh * (0.075f * kbq[0][ii] + 0.225f * kv);
                        } else if (s == 2) {
                            kbq[2][ii] = kv;
                            zsq[ii] = zc + hh * ((44.f / 45.f) * kbq[0][ii]
                                               - (56.f / 15.f) * kbq[1][ii]
                                               + (32.f / 9.f) * kv);
                        } else if (s == 3) {
                            kbq[3][ii] = kv;
                            zsq[ii] = zc + hh * ((19372.f / 6561.f) * kbq[0][ii]
                                               - (25360.f / 2187.f) * kbq[1][ii]
                                               + (64448.f / 6561.f) * kbq[2][ii]
                                               - (212.f / 729.f) * kv);
                        } else if (s == 4) {
                            kbq[4][ii] = kv;
                            zsq[ii] = zc + hh * ((9017.f / 3168.f) * kbq[0][ii]
                                               - (355.f / 33.f) * kbq[1][ii]
                                               + (46732.f / 5247.f) * kbq[2][ii]
                                               + (49.f / 176.f) * kbq[3][ii]
                                               - (5103.f / 18656.f) * kv);
                        } else {
                            z[q * ZPB + ii] = zc + hh * ((35.f / 384.f) * kbq[0][ii]
                                                       + (500.f / 1113.f) * kbq[2][ii]
                                                       + (125.f / 192.f) * kbq[3][ii]
                                                       - (2187.f / 6784.f) * kbq[4][ii]
                                                       + (11.f / 84.f) * kv);
                        }
                    }
                }
                __syncthreads();
            }   // stages
        }       // substeps

        // ---- per-interval z-exchange (full z needed only for readout) ----
        epoch++;
        if (tid < ZPB)
            __hip_atomic_store(&kx[kxbase(q) + tid], z[q * ZPB + tid],
                               __ATOMIC_RELAXED, __HIP_MEMORY_SCOPE_AGENT);
        __syncthreads();
        if (tid == 0)
            __hip_atomic_store(&seq[(b * NB + q) * 16], (unsigned)epoch,
                               __ATOMIC_RELAXED, __HIP_MEMORY_SCOPE_AGENT);
        asm volatile("" ::: "memory");
        if (tid < NB && tid != q && !dead) {
            unsigned* sp = &seq[(b * NB + tid) * 16];
            int guard = 0;
            while (__hip_atomic_load(sp, __ATOMIC_RELAXED,
                                     __HIP_MEMORY_SCOPE_AGENT) < (unsigned)epoch) {
                __builtin_amdgcn_s_sleep(1);
                if (++guard > (1 << 20)) { dead = true; break; }
            }
        }
        __syncthreads();
        if (tid < H_) {
            int qq = tid >> 6, e = tid & 63;
            if (qq != q)
                z[tid] = __hip_atomic_load(&kx[kxbase(qq) + e],
                                           __ATOMIC_RELAXED, __HIP_MEMORY_SCOPE_AGENT);
        }
        __syncthreads();
        readout(i + 1);
    }
}

// ---------------------------------------------------------------------------
// Fallback (ws too small): monolithic kernel, original weight layouts.
// ---------------------------------------------------------------------------
__global__ __launch_bounds__(NT) void gru_cde_mono(
    const float* __restrict__ y_past, const float* __restrict__ tvals,
    const float* __restrict__ cx,
    const float* __restrict__ wih, const float* __restrict__ whh,
    const float* __restrict__ gru_b, const float* __restrict__ gru_bn,
    const float* __restrict__ w0, const float* __restrict__ b0,
    const float* __restrict__ w1, const float* __restrict__ b1,
    const float* __restrict__ w2, const float* __restrict__ b2,
    const float* __restrict__ ro_w, const float* __restrict__ ro_b,
    float* __restrict__ out)
{
    const int b   = blockIdx.x;
    const int tid = threadIdx.x;

    __shared__ __align__(16) float z[H_];
    __shared__ float zsv[H_];
    __shared__ float kbv[6][H_];
    __shared__ float a0v[W_];
    __shared__ float a1v[W_];
    __shared__ float redv[8][W_];
    __shared__ float gsum[GR_];
    __shared__ float gaux[H_];
    __shared__ float xb[S_ + XC_];
    __shared__ float dxsv[XC_];

    const float gb_t = (tid < GR_) ? gru_b[tid] : 0.f;
    const float bn_t = (tid < H_) ? gru_bn[tid] : 0.f;
    const float4 bb = reinterpret_cast<const float4*>(b2)[tid];

    if (tid < H_) z[tid] = 0.f;
    __syncthreads();

    for (int step = 0; step < L_IN; ++step) {
        if (tid < S_ + XC_) {
            float v;
            if (tid < S_)                v = y_past[(b * L_IN + step) * S_ + tid];
            else if (tid < S_ + XC_ - 1) v = cx[(b * T_ + step) * (XC_ - 1) + (tid - S_)];
            else                         v = tvals[step];
            xb[tid] = v;
        }
        __syncthreads();
        if (tid < GR_) {
            float ig = gb_t;
            #pragma unroll
            for (int k = 0; k < S_ + XC_; ++k) ig += wih[tid * (S_ + XC_) + k] * xb[k];
            float hg = 0.f;
            #pragma unroll 8
            for (int k = 0; k < H_; ++k) hg += whh[tid * H_ + k] * z[k];
            if (tid < 2 * H_) gsum[tid] = ig + hg;
            else { gsum[tid] = ig; gaux[tid - 2 * H_] = hg; }
        }
        __syncthreads();
        if (tid < H_) {
            float r = sigmoid_f(gsum[tid]);
            float u = sigmoid_f(gsum[tid + H_]);
            float n = tanhf(gsum[tid + 2 * H_] + r * (gaux[tid] + bn_t));
            z[tid] = n + u * (z[tid] - n);
        }
        __syncthreads();
    }

    auto readout = [&](int idx) {
        if (tid < 8 * 64) {
            int o  = tid >> 6;
            int kk = tid & 63;
            float4 wv = reinterpret_cast<const float4*>(ro_w)[o * 64 + kk];
            float4 zv = *reinterpret_cast<const float4*>(&z[kk * 4]);
            float p = wv.x * zv.x + wv.y * zv.y + wv.z * zv.z + wv.w * zv.w;
            p += __shfl_xor(p, 1);
            p += __shfl_xor(p, 2);
            p += __shfl_xor(p, 4);
            p += __shfl_xor(p, 8);
            p += __shfl_xor(p, 16);
            p += __shfl_xor(p, 32);
            if (kk == 0) out[(b * L_IN + idx) * O_ + o] = p + ro_b[o];
        }
    };

    readout(0);

    auto vf = [&](const float* zin, int s) {
        const int g = tid >> 7;
        const int r = tid & 127;
        {
            float acc = 0.f;
            const int k0 = g * 32;
            #pragma unroll 8
            for (int k = k0; k < k0 + 32; ++k) acc += w0[r * H_ + k] * zin[k];
            redv[g][r] = acc;
        }
        __syncthreads();
        if (tid < W_) {
            float sa = b0[tid];
            #pragma unroll
            for (int gg = 0; gg < 8; ++gg) sa += redv[gg][tid];
            a0v[tid] = softplus_f(sa);
        }
        __syncthreads();
        {
            float acc = 0.f;
            const int k0 = g * 16;
            #pragma unroll
            for (int k = k0; k < k0 + 16; ++k) acc += w1[r * W_ + k] * a0v[k];
            redv[g][r] = acc;
        }
        __syncthreads();
        if (tid < W_) {
            float sa = b1[tid];
            #pragma unroll
            for (int gg = 0; gg < 8; ++gg) sa += redv[gg][tid];
            a1v[tid] = softplus_f(sa);
        }
        __syncthreads();
        {
            float4 acc = make_float4(0.f, 0.f, 0.f, 0.f);
            const int jj = tid * 4;
            #pragma unroll 4
            for (int k = 0; k < W_; ++k) {
                float av = a1v[k];
                acc.x += w2[(jj + 0) * W_ + k] * av;
                acc.y += w2[(jj + 1) * W_ + k] * av;
                acc.z += w2[(jj + 2) * W_ + k] * av;
                acc.w += w2[(jj + 3) * W_ + k] * av;
            }
            const int c0 = jj & 15;
            float p = tanhf(acc.x + bb.x) * dxsv[c0]
                    + tanhf(acc.y + bb.y) * dxsv[c0 + 1]
                    + tanhf(acc.z + bb.z) * dxsv[c0 + 2]
                    + tanhf(acc.w + bb.w) * dxsv[c0 + 3];
            p += __shfl_xor(p, 1);
            p += __shfl_xor(p, 2);
            if ((tid & 3) == 0) kbv[s][tid >> 2] = p;
        }
        __syncthreads();
    };

    for (int i = 0; i < T_ - L_IN - 1; ++i) {
        float dt = tvals[L_IN + i + 1] - tvals[L_IN + i];
        if (tid < XC_) {
            float xa, xbv;
            if (tid < XC_ - 1) {
                xa  = cx[(b * T_ + L_IN + i) * (XC_ - 1) + tid];
                xbv = cx[(b * T_ + L_IN + i + 1) * (XC_ - 1) + tid];
            } else {
                xa  = tvals[L_IN + i];
                xbv = tvals[L_IN + i + 1];
            }
            dxsv[tid] = (xbv - xa) / dt;
        }
        const float hh = dt * 0.5f;
        __syncthreads();

        for (int sub = 0; sub < 2; ++sub) {
            vf(z, 0);
            if (tid < H_) zsv[tid] = z[tid] + hh * (0.2f * kbv[0][tid]);
            __syncthreads();
            vf(zsv, 1);
            if (tid < H_) zsv[tid] = z[tid] + hh * (0.075f * kbv[0][tid] + 0.225f * kbv[1][tid]);
            __syncthreads();
            vf(zsv, 2);
            if (tid < H_) zsv[tid] = z[tid] + hh * ((44.f / 45.f) * kbv[0][tid]
                                                - (56.f / 15.f) * kbv[1][tid]
                                                + (32.f / 9.f) * kbv[2][tid]);
            __syncthreads();
            vf(zsv, 3);
            if (tid < H_) zsv[tid] = z[tid] + hh * ((19372.f / 6561.f) * kbv[0][tid]
                                                - (25360.f / 2187.f) * kbv[1][tid]
                                                + (64448.f / 6561.f) * kbv[2][tid]
                                                - (212.f / 729.f) * kbv[3][tid]);
            __syncthreads();
            vf(zsv, 4);
            if (tid < H_) zsv[tid] = z[tid] + hh * ((9017.f / 3168.f) * kbv[0][tid]
                                                - (355.f / 33.f) * kbv[1][tid]
                                                + (46732.f / 5247.f) * kbv[2][tid]
                                                + (49.f / 176.f) * kbv[3][tid]
                                                - (5103.f / 18656.f) * kbv[4][tid]);
            __syncthreads();
            vf(zsv, 5);
            if (tid < H_) {
                z[tid] = z[tid] + hh * ((35.f / 384.f) * kbv[0][tid]
                                      + (500.f / 1113.f) * kbv[2][tid]
                                      + (125.f / 192.f) * kbv[3][tid]
                                      - (2187.f / 6784.f) * kbv[4][tid]
                                      + (11.f / 84.f) * kbv[5][tid]);
            }
            __syncthreads();
        }
        readout(i + 1);
    }
}

extern "C" void kernel_launch(void* const* d_in, const int* in_sizes, int n_in,
                              void* d_out, int out_size, void* d_ws, size_t ws_size,
                              hipStream_t stream) {
    const float* y_past = (const float*)d_in[0];
    const float* tvals  = (const float*)d_in[1];
    const float* cx     = (const float*)d_in[2];
    const float* wih    = (const float*)d_in[3];
    const float* whh    = (const float*)d_in[4];
    const float* gb     = (const float*)d_in[5];
    const float* gbn    = (const float*)d_in[6];
    const float* w0     = (const float*)d_in[7];
    const float* b0     = (const float*)d_in[8];
    const float* w1     = (const float*)d_in[9];
    const float* b1     = (const float*)d_in[10];
    const float* w2     = (const float*)d_in[11];
    const float* b2     = (const float*)d_in[12];
    const float* ro_w   = (const float*)d_in[13];
    const float* ro_b   = (const float*)d_in[14];
    float* out = (float*)d_out;

    if (ws_size >= WS_FLOATS * sizeof(float)) {
        float* ws = (float*)d_ws;
        auto launchT = [&](const float* in, float* o, int R, int K) {
            int n = R * K;
            transpose_kernel<<<(n + 255) / 256, 256, 0, stream>>>(in, o, R, K);
        };
        launchT(wih, ws + OFF_WIHT, GR_, S_ + XC_);
        launchT(whh, ws + OFF_WHHT, GR_, H_);
        launchT(w2,  ws + OFF_W2T,  HXC, W_);
        int nseq = B_ * NB * 16;
        init_seq_kernel<<<(nseq + 255) / 256, 256, 0, stream>>>(
            (unsigned*)(ws + OFF_SEQ), nseq);
        gru_cde_dist<<<B_ * NB, NT, 0, stream>>>(
            y_past, tvals, cx,
            ws + OFF_WIHT, ws + OFF_WHHT, gb, gbn,
            w0, b0, w1, b1, ws + OFF_W2T, b2,
            ro_w, ro_b, ws + OFF_KX, (unsigned*)(ws + OFF_SEQ), out);
    } else {
        gru_cde_mono<<<B_, NT, 0, stream>>>(
            y_past, tvals, cx,
            wih, whh, gb, gbn,
            w0, b0, w1, b1, w2, b2,
            ro_w, ro_b, out);
    }
}

// Round 8
// 9631.408 us; speedup vs baseline: 2.4795x; 1.4500x over previous
//
#include <hip/hip_runtime.h>
#include <math.h>

// Problem constants (match reference)
constexpr int B_   = 64;
constexpr int T_   = 200;
constexpr int L_IN = 100;
constexpr int S_   = 8;
constexpr int XC_  = 16;
constexpr int H_   = 256;
constexpr int W_   = 128;
constexpr int O_   = 8;
constexpr int GR_  = 3 * H_;      // 768
constexpr int HXC  = H_ * XC_;    // 4096

constexpr int NB   = 4;           // blocks per batch (team)
constexpr int ZPB  = 64;          // z-rows per block
constexpr int SLOT = 128;         // exchange payload slot (u64 elements)

#define NT 1024

// Workspace layout (floats)
constexpr size_t OFF_WIHT = 0;                               // [24][768]
constexpr size_t OFF_WHHT = OFF_WIHT + 24ull * GR_;          // [256][768]
constexpr size_t OFF_W2T  = OFF_WHHT + (size_t)H_ * GR_;     // [128][4096] k-major
constexpr size_t OFF_KX   = OFF_W2T + (size_t)W_ * HXC;      // [64][2][4][128] u64
constexpr size_t KX_U64   = (size_t)B_ * 2 * NB * SLOT;      // 65536 u64
constexpr size_t WS_FLOATS = OFF_KX + KX_U64 * 2;            // ~3.48 MB

// Transpose: in is R x K row-major; out[k*R + j] = in[j*K + k]
__global__ void transpose_kernel(const float* __restrict__ in, float* __restrict__ out,
                                 int R, int K) {
    int o = blockIdx.x * blockDim.x + threadIdx.x;
    if (o < R * K) {
        int k = o / R;
        int j = o - k * R;
        out[o] = in[j * K + k];
    }
}

__device__ __forceinline__ float softplus_f(float x) {
    return fmaxf(x, 0.f) + log1pf(expf(-fabsf(x)));
}
__device__ __forceinline__ float sigmoid_f(float x) {
    return 1.f / (1.f + expf(-x));
}

// ---------------------------------------------------------------------------
// R8: 4-block teams {b,b+64,b+128,b+192}, distributed state.
// Exchange = packed (epoch,value) u64 relaxed agent atomics: ONE round trip,
// atomicity pairs tag+value (no flag handshake, no fences, no L2 invalidation).
// Weights: named-float4 registers (no indexed arrays -> no scratch spill) +
// 128 KB LDS W2 tile; only 256 KB/vf streamed from L2.
// LDS ~151 KB forces 1 block/CU (stable placement, R7-proven).
// ---------------------------------------------------------------------------
__global__ __launch_bounds__(NT, 4) void gru_cde_dist(
    const float* __restrict__ y_past,   // [B][L_IN][S]
    const float* __restrict__ tvals,    // [T]
    const float* __restrict__ cx,       // [B][T][XC-1]
    const float* __restrict__ wihT,     // [24][768]
    const float* __restrict__ whhT,     // [256][768]
    const float* __restrict__ gru_b,    // [768]
    const float* __restrict__ gru_bn,   // [256]
    const float* __restrict__ w0,       // [128][256] row-major
    const float* __restrict__ b0,       // [128]
    const float* __restrict__ w1,       // [128][128] row-major
    const float* __restrict__ b1,       // [128]
    const float* __restrict__ w2T,      // [128][4096] k-major
    const float* __restrict__ b2,       // [4096]
    const float* __restrict__ ro_w,     // [8][256]
    const float* __restrict__ ro_b,     // [8]
    unsigned long long* __restrict__ kx, // [64][2][4][128] tagged payload
    float* __restrict__ out)            // [B][100][8]
{
    const int b   = blockIdx.x & (B_ - 1);   // batch
    const int q   = blockIdx.x >> 6;         // quarter 0..3
    const int tid = threadIdx.x;

    __shared__ __align__(16) float z[H_];
    __shared__ __align__(16) float zsq[ZPB];
    __shared__ float kbq[5][ZPB];
    __shared__ __align__(16) float a0s[W_];
    __shared__ __align__(16) float a1s[W_];
    __shared__ float vown[W_];
    __shared__ float red[3][W_];
    __shared__ __align__(16) float4 red4[4][256];
    __shared__ float gsum[192];
    __shared__ float gaux[ZPB];
    __shared__ float xb[S_ + XC_];
    __shared__ float dxs[XC_];
    __shared__ __align__(16) float4 w2lds[4][8][256];   // 128 KB: 32 W2 k-planes

    int  epoch = 0;
    bool dead  = false;
    float hh   = 0.f;

    auto slotbase = [&](int qq) -> size_t {
        return (((size_t)b * 2 + (epoch & 1)) * NB + qq) * SLOT;
    };
    auto publish_u64 = [&](int elem, float v) {
        unsigned long long pk = ((unsigned long long)(unsigned)epoch << 32)
                              | (unsigned long long)__float_as_uint(v);
        __hip_atomic_store(&kx[slotbase(q) + elem], pk,
                           __ATOMIC_RELAXED, __HIP_MEMORY_SCOPE_AGENT);
    };
    auto poll_u64 = [&](int qq, int elem) -> float {
        unsigned long long pk = 0;
        int guard = 0;
        for (;;) {
            pk = __hip_atomic_load(&kx[slotbase(qq) + elem],
                                   __ATOMIC_RELAXED, __HIP_MEMORY_SCOPE_AGENT);
            if ((unsigned)(pk >> 32) >= (unsigned)epoch) break;
            if (++guard > (1 << 20)) { dead = true; break; }
        }
        return __uint_as_float((unsigned)pk);
    };

    // ---------------- Encoder: 100 GRU steps, 2 syncs/step -------------------
    const int   seg = tid >> 6;          // 0=reset,1=update,2=new (tid<192)
    const int   l63 = tid & 63;
    const int   grow = seg * H_ + q * ZPB + l63;
    const float gbr = (tid < 192) ? gru_b[grow] : 0.f;
    const float bnr = (tid < ZPB) ? gru_bn[q * ZPB + tid] : 0.f;

    if (tid < H_) z[tid] = 0.f;
    if (tid < S_ + XC_) {    // xb for step 0
        float v;
        if (tid < S_)                v = y_past[(b * L_IN) * S_ + tid];
        else if (tid < S_ + XC_ - 1) v = cx[(b * T_) * (XC_ - 1) + (tid - S_)];
        else                         v = tvals[0];
        xb[tid] = v;
    }
    __syncthreads();

    for (int step = 0; step < L_IN; ++step) {
        if (tid < 192) {    // phase A: gate pre-activations
            float ig = gbr;
            #pragma unroll
            for (int k = 0; k < S_ + XC_; ++k) ig += wihT[k * GR_ + grow] * xb[k];
            float hg = 0.f, hg2 = 0.f;
            #pragma unroll 8
            for (int k = 0; k < H_; k += 2) {
                hg  += whhT[k * GR_ + grow]       * z[k];
                hg2 += whhT[(k + 1) * GR_ + grow] * z[k + 1];
            }
            hg += hg2;
            if (seg < 2) gsum[tid] = ig + hg;
            else { gsum[tid] = ig; gaux[l63] = hg; }
        }
        __syncthreads();
        epoch++;
        // phase B: update+publish / gather / preload xb
        if (tid < ZPB) {
            float rr = sigmoid_f(gsum[tid]);
            float uu = sigmoid_f(gsum[64 + tid]);
            float nn = tanhf(gsum[128 + tid] + rr * (gaux[tid] + bnr));
            float zo = z[q * ZPB + tid];
            float znew = nn + uu * (zo - nn);
            z[q * ZPB + tid] = znew;
            publish_u64(tid, znew);
        } else if (tid < 256) {
            if (!dead) {
                int pp = tid >> 6;               // 1..3
                int qq = (q + pp) & 3;
                int e  = tid & 63;
                float v = poll_u64(qq, e);
                z[qq * 64 + e] = v;
            }
        } else if (tid < 256 + S_ + XC_ && step + 1 < L_IN) {
            int c = tid - 256;
            float v;
            if (c < S_)                v = y_past[(b * L_IN + step + 1) * S_ + c];
            else if (c < S_ + XC_ - 1) v = cx[(b * T_ + step + 1) * (XC_ - 1) + (c - S_)];
            else                       v = tvals[step + 1];
            xb[c] = v;
        }
        __syncthreads();
    }

    // readout (block q==0 only; its z is full after encoder gathers)
    auto readout = [&](int idx) {
        if (q == 0 && tid < 8 * 64) {
            int o  = tid >> 6;
            int kk = tid & 63;
            float4 wv = reinterpret_cast<const float4*>(ro_w)[o * 64 + kk];
            float4 zv = *reinterpret_cast<const float4*>(&z[kk * 4]);
            float p = wv.x * zv.x + wv.y * zv.y + wv.z * zv.z + wv.w * zv.w;
            p += __shfl_xor(p, 1);
            p += __shfl_xor(p, 2);
            p += __shfl_xor(p, 4);
            p += __shfl_xor(p, 8);
            p += __shfl_xor(p, 16);
            p += __shfl_xor(p, 32);
            if (kk == 0) out[(b * L_IN + idx) * O_ + o] = p + ro_b[o];
        }
    };

    readout(0);

    // ---------------- ODE weight residency (NAMED regs -> no spill) ----------
    const int wv_ = tid >> 6;            // wave 0..15
    const int ln  = tid & 63;            // lane
    const int vr  = wv_ * 8 + (ln >> 3); // matvec row 0..127
    const int vc  = ln & 7;              // k-chunk 0..7
    const int g2  = tid >> 8;            // W2 k-group 0..3
    const int u   = tid & 255;           // W2 row-quad 0..255

    const float4* __restrict__ w04  = reinterpret_cast<const float4*>(w0);
    const float4* __restrict__ w14  = reinterpret_cast<const float4*>(w1);
    const float4* __restrict__ w2T4 = reinterpret_cast<const float4*>(w2T);

    // W0 row vr, cols q*64 + vc*8 .. +7  (8 floats)
    const float4 w0r0 = w04[vr * 64 + q * 16 + vc * 2];
    const float4 w0r1 = w04[vr * 64 + q * 16 + vc * 2 + 1];
    // W1 row vr, cols vc*16 .. +15  (16 floats)
    const float4 w1r0 = w14[vr * 32 + vc * 4 + 0];
    const float4 w1r1 = w14[vr * 32 + vc * 4 + 1];
    const float4 w1r2 = w14[vr * 32 + vc * 4 + 2];
    const float4 w1r3 = w14[vr * 32 + vc * 4 + 3];
    // W2 reg planes j=0..7 of k-group g2 (rows 4u..4u+3 of block slice)
    const size_t w2base = (size_t)g2 * 32 * 1024 + (size_t)q * 256 + u;
    const float4 w2c0 = w2T4[w2base + 0 * 1024];
    const float4 w2c1 = w2T4[w2base + 1 * 1024];
    const float4 w2c2 = w2T4[w2base + 2 * 1024];
    const float4 w2c3 = w2T4[w2base + 3 * 1024];
    const float4 w2c4 = w2T4[w2base + 4 * 1024];
    const float4 w2c5 = w2T4[w2base + 5 * 1024];
    const float4 w2c6 = w2T4[w2base + 6 * 1024];
    const float4 w2c7 = w2T4[w2base + 7 * 1024];
    // W2 LDS planes j=8..15 of each k-group (32 planes, 128 KB), loaded once
    for (int it = 0; it < 8; ++it) {
        int L   = it * 1024 + tid;
        int g2l = L >> 11;
        int jl  = (L >> 8) & 7;
        int ul  = L & 255;
        w2lds[g2l][jl][ul] =
            w2T4[(size_t)(g2l * 32 + 8 + jl) * 1024 + (size_t)q * 256 + ul];
    }

    const float b0r = (tid < W_) ? b0[tid] : 0.f;
    const float b1r = b1[vr];
    float4 b2c = make_float4(0.f, 0.f, 0.f, 0.f);
    if (tid < 256) b2c = reinterpret_cast<const float4*>(b2)[q * 256 + tid];
    float4 dx4 = make_float4(0.f, 0.f, 0.f, 0.f);
    __syncthreads();   // w2lds ready

    // ---------------- ODE: 99 intervals x 2 dopri5 substeps ------------------
    for (int i = 0; i < T_ - L_IN - 1; ++i) {
        float dt = tvals[L_IN + i + 1] - tvals[L_IN + i];
        hh = dt * 0.5f;   // N_SUB = 2
        if (tid < XC_) {
            float xa, xbv;
            if (tid < XC_ - 1) {
                xa  = cx[(b * T_ + L_IN + i) * (XC_ - 1) + tid];
                xbv = cx[(b * T_ + L_IN + i + 1) * (XC_ - 1) + tid];
            } else {
                xa  = tvals[L_IN + i];
                xbv = tvals[L_IN + i + 1];
            }
            dxs[tid] = (xbv - xa) / dt;
        }
        __syncthreads();
        if (tid < 256) {
            int c0 = (tid & 3) * 4;
            dx4 = make_float4(dxs[c0], dxs[c0 + 1], dxs[c0 + 2], dxs[c0 + 3]);
        }

        for (int sub = 0; sub < 2; ++sub) {
            if (tid < ZPB) zsq[tid] = z[q * ZPB + tid];
            __syncthreads();

            for (int s = 0; s < 6; ++s) {
                epoch++;
                // ---- V: v-partial = W0own @ zsq, wave-shuffle reduce --------
                {
                    const float* zp = &zsq[vc * 8];
                    float pv = w0r0.x * zp[0] + w0r0.y * zp[1]
                             + w0r0.z * zp[2] + w0r0.w * zp[3]
                             + w0r1.x * zp[4] + w0r1.y * zp[5]
                             + w0r1.z * zp[6] + w0r1.w * zp[7];
                    pv += __shfl_xor(pv, 1);
                    pv += __shfl_xor(pv, 2);
                    pv += __shfl_xor(pv, 4);
                    if ((ln & 7) == 0) {
                        vown[vr] = pv;
                        publish_u64(vr, pv);
                    }
                }
                __syncthreads();   // 1
                // ---- GATHER: 384 threads, one tagged u64 each ---------------
                if (tid < 384 && !dead) {
                    int pp = tid >> 7;
                    int e  = tid & 127;
                    int qq = pp + (pp >= q);
                    red[pp][e] = poll_u64(qq, e);
                }
                __syncthreads();   // 2
                // ---- A0 ----------------------------------------------------
                if (tid < W_) {
                    float gv = vown[tid] + red[0][tid] + red[1][tid]
                             + red[2][tid] + b0r;
                    a0s[tid] = softplus_f(gv);
                }
                __syncthreads();   // 3
                // ---- A1: W1 @ a0, wave-shuffle reduce -----------------------
                {
                    const float4* ap = reinterpret_cast<const float4*>(a0s) + vc * 4;
                    float4 a0v = ap[0], a1v = ap[1], a2v = ap[2], a3v = ap[3];
                    float pa = w1r0.x * a0v.x + w1r0.y * a0v.y
                             + w1r0.z * a0v.z + w1r0.w * a0v.w
                             + w1r1.x * a1v.x + w1r1.y * a1v.y
                             + w1r1.z * a1v.z + w1r1.w * a1v.w
                             + w1r2.x * a2v.x + w1r2.y * a2v.y
                             + w1r2.z * a2v.z + w1r2.w * a2v.w
                             + w1r3.x * a3v.x + w1r3.y * a3v.y
                             + w1r3.z * a3v.z + w1r3.w * a3v.w;
                    pa += __shfl_xor(pa, 1);
                    pa += __shfl_xor(pa, 2);
                    pa += __shfl_xor(pa, 4);
                    if ((ln & 7) == 0) a1s[vr] = softplus_f(pa + b1r);
                }
                __syncthreads();   // 4
                // ---- W2: 8 reg + 8 LDS + 16 streamed planes -----------------
                {
                    const int base = g2 * 32;
                    float4 acc = make_float4(0.f, 0.f, 0.f, 0.f);
                    #define W2MAC(c_, idx_) { float av_ = a1s[base + (idx_)]; \
                        acc.x += (c_).x * av_; acc.y += (c_).y * av_; \
                        acc.z += (c_).z * av_; acc.w += (c_).w * av_; }
                    W2MAC(w2c0, 0) W2MAC(w2c1, 1) W2MAC(w2c2, 2) W2MAC(w2c3, 3)
                    W2MAC(w2c4, 4) W2MAC(w2c5, 5) W2MAC(w2c6, 6) W2MAC(w2c7, 7)
                    #pragma unroll
                    for (int jl = 0; jl < 8; ++jl) {
                        float4 wvv = w2lds[g2][jl][u];
                        float av = a1s[base + 8 + jl];
                        acc.x += wvv.x * av; acc.y += wvv.y * av;
                        acc.z += wvv.z * av; acc.w += wvv.w * av;
                    }
                    const float4* wp = w2T4 + (size_t)(base + 16) * 1024
                                     + (size_t)q * 256 + u;
                    #pragma unroll 4
                    for (int js = 0; js < 16; ++js) {
                        float4 wvv = wp[(size_t)js * 1024];
                        float av = a1s[base + 16 + js];
                        acc.x += wvv.x * av; acc.y += wvv.y * av;
                        acc.z += wvv.z * av; acc.w += wvv.w * av;
                    }
                    #undef W2MAC
                    red4[g2][u] = acc;
                }
                __syncthreads();   // 5
                // ---- COMBINE: k-reduce, tanh, dx-dot, state update ----------
                if (tid < 256) {
                    float4 t0 = red4[0][tid], t1 = red4[1][tid];
                    float4 t2 = red4[2][tid], t3 = red4[3][tid];
                    float p = tanhf(t0.x + t1.x + t2.x + t3.x + b2c.x) * dx4.x
                            + tanhf(t0.y + t1.y + t2.y + t3.y + b2c.y) * dx4.y
                            + tanhf(t0.z + t1.z + t2.z + t3.z + b2c.z) * dx4.z
                            + tanhf(t0.w + t1.w + t2.w + t3.w + b2c.w) * dx4.w;
                    p += __shfl_xor(p, 1);
                    p += __shfl_xor(p, 2);
                    if ((tid & 3) == 0) {
                        int ii = tid >> 2;
                        float kv = p;
                        float zc = z[q * ZPB + ii];
                        if (s == 0) {
                            kbq[0][ii] = kv;
                            zsq[ii] = zc + hh * (0.2f * kv);
                        } else if (s == 1) {
                            kbq[1][ii] = kv;
                            zsq[ii] = zc + hh * (0.075f * kbq[0][ii] + 0.225f * kv);
                        } else if (s == 2) {
                            kbq[2][ii] = kv;
                            zsq[ii] = zc + hh * ((44.f / 45.f) * kbq[0][ii]
                                               - (56.f / 15.f) * kbq[1][ii]
                                               + (32.f / 9.f) * kv);
                        } else if (s == 3) {
                            kbq[3][ii] = kv;
                            zsq[ii] = zc + hh * ((19372.f / 6561.f) * kbq[0][ii]
                                               - (25360.f / 2187.f) * kbq[1][ii]
                                               + (64448.f / 6561.f) * kbq[2][ii]
                                               - (212.f / 729.f) * kv);
                        } else if (s == 4) {
                            kbq[4][ii] = kv;
                            zsq[ii] = zc + hh * ((9017.f / 3168.f) * kbq[0][ii]
                                               - (355.f / 33.f) * kbq[1][ii]
                                               + (46732.f / 5247.f) * kbq[2][ii]
                                               + (49.f / 176.f) * kbq[3][ii]
                                               - (5103.f / 18656.f) * kv);
                        } else {
                            z[q * ZPB + ii] = zc + hh * ((35.f / 384.f) * kbq[0][ii]
                                                       + (500.f / 1113.f) * kbq[2][ii]
                                                       + (125.f / 192.f) * kbq[3][ii]
                                                       - (2187.f / 6784.f) * kbq[4][ii]
                                                       + (11.f / 84.f) * kv);
                        }
                    }
                }
                __syncthreads();   // 6
            }   // stages
        }       // substeps

        // ---- z to block 0 for readout (one-way) ----
        epoch++;
        if (tid < ZPB) publish_u64(tid, z[q * ZPB + tid]);
        if (q == 0 && tid >= 64 && tid < 256 && !dead) {
            int pp = tid >> 6;       // 1..3
            int e  = tid & 63;
            z[pp * 64 + e] = poll_u64(pp, e);
        }
        __syncthreads();
        readout(i + 1);
    }
}

// ---------------------------------------------------------------------------
// Fallback (ws too small): monolithic kernel, original weight layouts.
// ---------------------------------------------------------------------------
__global__ __launch_bounds__(NT) void gru_cde_mono(
    const float* __restrict__ y_past, const float* __restrict__ tvals,
    const float* __restrict__ cx,
    const float* __restrict__ wih, const float* __restrict__ whh,
    const float* __restrict__ gru_b, const float* __restrict__ gru_bn,
    const float* __restrict__ w0, const float* __restrict__ b0,
    const float* __restrict__ w1, const float* __restrict__ b1,
    const float* __restrict__ w2, const float* __restrict__ b2,
    const float* __restrict__ ro_w, const float* __restrict__ ro_b,
    float* __restrict__ out)
{
    const int b   = blockIdx.x;
    const int tid = threadIdx.x;

    __shared__ __align__(16) float z[H_];
    __shared__ float zsv[H_];
    __shared__ float kbv[6][H_];
    __shared__ float a0v[W_];
    __shared__ float a1v[W_];
    __shared__ float redv[8][W_];
    __shared__ float gsum[GR_];
    __shared__ float gaux[H_];
    __shared__ float xb[S_ + XC_];
    __shared__ float dxsv[XC_];

    const float gb_t = (tid < GR_) ? gru_b[tid] : 0.f;
    const float bn_t = (tid < H_) ? gru_bn[tid] : 0.f;
    const float4 bb = reinterpret_cast<const float4*>(b2)[tid];

    if (tid < H_) z[tid] = 0.f;
    __syncthreads();

    for (int step = 0; step < L_IN; ++step) {
        if (tid < S_ + XC_) {
            float v;
            if (tid < S_)                v = y_past[(b * L_IN + step) * S_ + tid];
            else if (tid < S_ + XC_ - 1) v = cx[(b * T_ + step) * (XC_ - 1) + (tid - S_)];
            else                         v = tvals[step];
            xb[tid] = v;
        }
        __syncthreads();
        if (tid < GR_) {
            float ig = gb_t;
            #pragma unroll
            for (int k = 0; k < S_ + XC_; ++k) ig += wih[tid * (S_ + XC_) + k] * xb[k];
            float hg = 0.f;
            #pragma unroll 8
            for (int k = 0; k < H_; ++k) hg += whh[tid * H_ + k] * z[k];
            if (tid < 2 * H_) gsum[tid] = ig + hg;
            else { gsum[tid] = ig; gaux[tid - 2 * H_] = hg; }
        }
        __syncthreads();
        if (tid < H_) {
            float r = sigmoid_f(gsum[tid]);
            float u = sigmoid_f(gsum[tid + H_]);
            float n = tanhf(gsum[tid + 2 * H_] + r * (gaux[tid] + bn_t));
            z[tid] = n + u * (z[tid] - n);
        }
        __syncthreads();
    }

    auto readout = [&](int idx) {
        if (tid < 8 * 64) {
            int o  = tid >> 6;
            int kk = tid & 63;
            float4 wv = reinterpret_cast<const float4*>(ro_w)[o * 64 + kk];
            float4 zv = *reinterpret_cast<const float4*>(&z[kk * 4]);
            float p = wv.x * zv.x + wv.y * zv.y + wv.z * zv.z + wv.w * zv.w;
            p += __shfl_xor(p, 1);
            p += __shfl_xor(p, 2);
            p += __shfl_xor(p, 4);
            p += __shfl_xor(p, 8);
            p += __shfl_xor(p, 16);
            p += __shfl_xor(p, 32);
            if (kk == 0) out[(b * L_IN + idx) * O_ + o] = p + ro_b[o];
        }
    };

    readout(0);

    auto vf = [&](const float* zin, int s) {
        const int g = tid >> 7;
        const int r = tid & 127;
        {
            float acc = 0.f;
            const int k0 = g * 32;
            #pragma unroll 8
            for (int k = k0; k < k0 + 32; ++k) acc += w0[r * H_ + k] * zin[k];
            redv[g][r] = acc;
        }
        __syncthreads();
        if (tid < W_) {
            float sa = b0[tid];
            #pragma unroll
            for (int gg = 0; gg < 8; ++gg) sa += redv[gg][tid];
            a0v[tid] = softplus_f(sa);
        }
        __syncthreads();
        {
            float acc = 0.f;
            const int k0 = g * 16;
            #pragma unroll
            for (int k = k0; k < k0 + 16; ++k) acc += w1[r * W_ + k] * a0v[k];
            redv[g][r] = acc;
        }
        __syncthreads();
        if (tid < W_) {
            float sa = b1[tid];
            #pragma unroll
            for (int gg = 0; gg < 8; ++gg) sa += redv[gg][tid];
            a1v[tid] = softplus_f(sa);
        }
        __syncthreads();
        {
            float4 acc = make_float4(0.f, 0.f, 0.f, 0.f);
            const int jj = tid * 4;
            #pragma unroll 4
            for (int k = 0; k < W_; ++k) {
                float av = a1v[k];
                acc.x += w2[(jj + 0) * W_ + k] * av;
                acc.y += w2[(jj + 1) * W_ + k] * av;
                acc.z += w2[(jj + 2) * W_ + k] * av;
                acc.w += w2[(jj + 3) * W_ + k] * av;
            }
            const int c0 = jj & 15;
            float p = tanhf(acc.x + bb.x) * dxsv[c0]
                    + tanhf(acc.y + bb.y) * dxsv[c0 + 1]
                    + tanhf(acc.z + bb.z) * dxsv[c0 + 2]
                    + tanhf(acc.w + bb.w) * dxsv[c0 + 3];
            p += __shfl_xor(p, 1);
            p += __shfl_xor(p, 2);
            if ((tid & 3) == 0) kbv[s][tid >> 2] = p;
        }
        __syncthreads();
    };

    for (int i = 0; i < T_ - L_IN - 1; ++i) {
        float dt = tvals[L_IN + i + 1] - tvals[L_IN + i];
        if (tid < XC_) {
            float xa, xbv;
            if (tid < XC_ - 1) {
                xa  = cx[(b * T_ + L_IN + i) * (XC_ - 1) + tid];
                xbv = cx[(b * T_ + L_IN + i + 1) * (XC_ - 1) + tid];
            } else {
                xa  = tvals[L_IN + i];
                xbv = tvals[L_IN + i + 1];
            }
            dxsv[tid] = (xbv - xa) / dt;
        }
        const float hh = dt * 0.5f;
        __syncthreads();

        for (int sub = 0; sub < 2; ++sub) {
            vf(z, 0);
            if (tid < H_) zsv[tid] = z[tid] + hh * (0.2f * kbv[0][tid]);
            __syncthreads();
            vf(zsv, 1);
            if (tid < H_) zsv[tid] = z[tid] + hh * (0.075f * kbv[0][tid] + 0.225f * kbv[1][tid]);
            __syncthreads();
            vf(zsv, 2);
            if (tid < H_) zsv[tid] = z[tid] + hh * ((44.f / 45.f) * kbv[0][tid]
                                                - (56.f / 15.f) * kbv[1][tid]
                                                + (32.f / 9.f) * kbv[2][tid]);
            __syncthreads();
            vf(zsv, 3);
            if (tid < H_) zsv[tid] = z[tid] + hh * ((19372.f / 6561.f) * kbv[0][tid]
                                                - (25360.f / 2187.f) * kbv[1][tid]
                                                + (64448.f / 6561.f) * kbv[2][tid]
                                                - (212.f / 729.f) * kbv[3][tid]);
            __syncthreads();
            vf(zsv, 4);
            if (tid < H_) zsv[tid] = z[tid] + hh * ((9017.f / 3168.f) * kbv[0][tid]
                                                - (355.f / 33.f) * kbv[1][tid]
                                                + (46732.f / 5247.f) * kbv[2][tid]
                                                + (49.f / 176.f) * kbv[3][tid]
                                                - (5103.f / 18656.f) * kbv[4][tid]);
            __syncthreads();
            vf(zsv, 5);
            if (tid < H_) {
                z[tid] = z[tid] + hh * ((35.f / 384.f) * kbv[0][tid]
                                      + (500.f / 1113.f) * kbv[2][tid]
                                      + (125.f / 192.f) * kbv[3][tid]
                                      - (2187.f / 6784.f) * kbv[4][tid]
                                      + (11.f / 84.f) * kbv[5][tid]);
            }
            __syncthreads();
        }
        readout(i + 1);
    }
}

extern "C" void kernel_launch(void* const* d_in, const int* in_sizes, int n_in,
                              void* d_out, int out_size, void* d_ws, size_t ws_size,
                              hipStream_t stream) {
    const float* y_past = (const float*)d_in[0];
    const float* tvals  = (const float*)d_in[1];
    const float* cx     = (const float*)d_in[2];
    const float* wih    = (const float*)d_in[3];
    const float* whh    = (const float*)d_in[4];
    const float* gb     = (const float*)d_in[5];
    const float* gbn    = (const float*)d_in[6];
    const float* w0     = (const float*)d_in[7];
    const float* b0     = (const float*)d_in[8];
    const float* w1     = (const float*)d_in[9];
    const float* b1     = (const float*)d_in[10];
    const float* w2     = (const float*)d_in[11];
    const float* b2     = (const float*)d_in[12];
    const float* ro_w   = (const float*)d_in[13];
    const float* ro_b   = (const float*)d_in[14];
    float* out = (float*)d_out;

    if (ws_size >= WS_FLOATS * sizeof(float)) {
        float* ws = (float*)d_ws;
        auto launchT = [&](const float* in, float* o, int R, int K) {
            int n = R * K;
            transpose_kernel<<<(n + 255) / 256, 256, 0, stream>>>(in, o, R, K);
        };
        launchT(wih, ws + OFF_WIHT, GR_, S_ + XC_);
        launchT(whh, ws + OFF_WHHT, GR_, H_);
        launchT(w2,  ws + OFF_W2T,  HXC, W_);
        // zero the tagged-exchange buffer (tags must start below epoch 1)
        hipMemsetAsync((char*)d_ws + OFF_KX * sizeof(float), 0,
                       KX_U64 * sizeof(unsigned long long), stream);
        gru_cde_dist<<<B_ * NB, NT, 0, stream>>>(
            y_past, tvals, cx,
            ws + OFF_WIHT, ws + OFF_WHHT, gb, gbn,
            w0, b0, w1, b1, ws + OFF_W2T, b2,
            ro_w, ro_b,
            (unsigned long long*)(ws + OFF_KX), out);
    } else {
        gru_cde_mono<<<B_, NT, 0, stream>>>(
            y_past, tvals, cx,
            wih, whh, gb, gbn,
            w0, b0, w1, b1, w2, b2,
            ro_w, ro_b, out);
    }
}